// Round 5
// baseline (249.927 us; speedup 1.0000x reference)
//
#include <hip/hip_runtime.h>

#define BINS   10
#define CSHIFT 26
#define QMASK  0x03FFFFFFu
#define QSCALE 2097152.0f        // 2^21 quanta per loss unit
#define QLN2   1453635.25f       // ln2 * 2^21: q = log2(1+em) * QLN2

typedef float vf4 __attribute__((ext_vector_type(4)));
typedef int   vi4 __attribute__((ext_vector_type(4)));

// ws layout (CUMULATIVE over bins): float qsum[10] @ 0, unsigned cnt[10] @ 64.
// Re-poisoned 0xAA each replay -> zero each launch.

__global__ void ghm_zero_ws(unsigned* ws) {
    if (threadIdx.x < 32) ws[threadIdx.x] = 0u;
}

// bin b <=> D[b+1] < d <= D[b], D[b] = ln(20/b - 1); cumulative A[b] over d>Th[b].
__device__ __forceinline__ void proc1(float o0, float o1, int t, unsigned* A) {
    const float Th[BINS] = {
        2.9444390f, 2.1972246f, 1.7346011f, 1.3862944f, 1.0986123f,
        0.8472979f, 0.6190392f, 0.4054651f, 0.2006707f, 0.0f };
    float s = o0 - o1;
    float d = __int_as_float(__float_as_int(s) ^ (t << 31));  // target - other
    float em   = __expf(-d);
    float onep = 1.0f + em;
    float qf   = fmaf(__log2f(onep), QLN2, 0.5f);   // round(loss * 2^21)
    unsigned val = (unsigned)qf + (1u << CSHIFT);   // garbage if d<=0: masked below
    #pragma unroll
    for (int b = 0; b < BINS; ++b)
        A[b] += (d > Th[b]) ? val : 0u;
}

__global__ __launch_bounds__(256, 4)
void ghm_main(const float* __restrict__ outs,   // [n,2]
              const int*   __restrict__ tgt,    // [n]
              float*       __restrict__ ws_q,
              unsigned*    __restrict__ ws_c,
              int n) {
    unsigned A[BINS];
    #pragma unroll
    for (int b = 0; b < BINS; ++b) A[b] = 0u;

    const int tid      = threadIdx.x;
    const int gid      = blockIdx.x * blockDim.x + tid;
    const int nthreads = gridDim.x * blockDim.x;
    const int npacks   = n >> 2;

    const vf4* outs4 = (const vf4*)outs;
    const vi4* tgt4  = (const vi4*)tgt;

    // Fast path: all 4 packs (16 samples) loaded up front — 12 independent
    // dwordx4 (12 KB/wave) in flight, one wait ladder per wave lifetime.
    int p = gid;
    if (p + 3 * nthreads < npacks) {
        vf4 oa[4], ob[4]; vi4 tt[4];
        #pragma unroll
        for (int k = 0; k < 4; ++k) {
            int pk = p + k * nthreads;
            oa[k] = __builtin_nontemporal_load(&outs4[2 * pk]);
            ob[k] = __builtin_nontemporal_load(&outs4[2 * pk + 1]);
            tt[k] = __builtin_nontemporal_load(&tgt4[pk]);
        }
        #pragma unroll
        for (int k = 0; k < 4; ++k) {
            proc1(oa[k].x, oa[k].y, tt[k].x, A);
            proc1(oa[k].z, oa[k].w, tt[k].y, A);
            proc1(ob[k].x, ob[k].y, tt[k].z, A);
            proc1(ob[k].z, ob[k].w, tt[k].w, A);
        }
        p += 4 * nthreads;
    }
    for (; p < npacks; p += nthreads) {            // generic remainder
        vf4 a0 = outs4[2 * p];
        vf4 a1 = outs4[2 * p + 1];
        vi4 t0 = tgt4[p];
        proc1(a0.x, a0.y, t0.x, A);
        proc1(a0.z, a0.w, t0.y, A);
        proc1(a1.x, a1.y, t0.z, A);
        proc1(a1.z, a1.w, t0.w, A);
    }
    int tail = n & 3;                              // scalar tail (0 here)
    if (gid < tail) {
        int s = (npacks << 2) + gid;
        proc1(outs[2 * s], outs[2 * s + 1], tgt[s], A);
    }

    // Epilogue: dump packed regs to LDS once, tree-reduce, 20 atomics/block.
    __shared__ unsigned h[BINS][256];   // 10 KB
    __shared__ unsigned s_c[BINS][16];
    __shared__ float    s_q[BINS][16];
    #pragma unroll
    for (int b = 0; b < BINS; ++b) h[b][tid] = A[b];
    __syncthreads();

    if (tid < 16 * BINS) {
        int bin  = tid >> 4;
        int part = tid & 15;
        unsigned c = 0, q = 0;                     // q <= 16*23.3M < 2^32
        #pragma unroll
        for (int j = 0; j < 16; ++j) {
            unsigned v = h[bin][j * 16 + part];
            c += v >> CSHIFT;
            q += v & QMASK;
        }
        s_c[bin][part] = c;
        s_q[bin][part] = (float)q;
    }
    __syncthreads();
    if (tid < BINS) {
        unsigned c = 0; float q = 0.0f;
        #pragma unroll
        for (int j = 0; j < 16; ++j) { c += s_c[tid][j]; q += s_q[tid][j]; }
        if (c) {
            atomicAdd(&ws_c[tid], c);
            atomicAdd(&ws_q[tid], q * (1.0f / QSCALE));  // loss units
        }
    }
}

__global__ void ghm_final(const float*    __restrict__ ws_q,
                          const unsigned* __restrict__ ws_c,
                          const float*    __restrict__ acc_sum,
                          float* __restrict__ out) {
    if (threadIdx.x == 0) {
        float r = 0.0f;
        float    pq = 0.0f;
        unsigned pc = 0u;
        #pragma unroll
        for (int b = 0; b < BINS; ++b) {          // cumulative -> per-bin diff
            float    cq = ws_q[b];
            unsigned cc = ws_c[b];
            unsigned cnt = cc - pc;
            float    qs  = cq - pq;
            pc = cc; pq = cq;
            if (cnt > 0u) {
                float na = 0.75f * acc_sum[b] + 0.25f * (float)cnt;
                r += qs / na;    // = (1/N) * sum(loss_i * N/na[bin_i])
            }
        }
        *out = r;
    }
}

extern "C" void kernel_launch(void* const* d_in, const int* in_sizes, int n_in,
                              void* d_out, int out_size, void* d_ws, size_t ws_size,
                              hipStream_t stream) {
    const float* outputs = (const float*)d_in[0];  // [N,2] f32
    const int*   targets = (const int*)d_in[1];    // [N] int32
    const float* acc_sum = (const float*)d_in[2];  // [10] f32
    int n = in_sizes[1];

    float*    ws_q = (float*)d_ws;
    unsigned* ws_c = (unsigned*)((char*)d_ws + 64);

    ghm_zero_ws<<<1, 64, 0, stream>>>((unsigned*)d_ws);
    // 4096 blocks = 2x oversubscription; 16 samples/thread, all loads up front.
    ghm_main<<<4096, 256, 0, stream>>>(outputs, targets, ws_q, ws_c, n);
    ghm_final<<<1, 64, 0, stream>>>(ws_q, ws_c, acc_sum, (float*)d_out);
}